// Round 2
// baseline (358.254 us; speedup 1.0000x reference)
//
#include <hip/hip_runtime.h>
#include <math.h>

#define B_    4
#define T_    8192
#define C_    1024
#define E_    64
#define NTOK  (B_*T_)          // 32768
#define KSEL  2

// d_out offsets (in floats): idx, scores, probs, importance, load
#define OFF_IDX    0
#define OFF_SCORES (NTOK*KSEL)               // 65536
#define OFF_PROBS  (2*NTOK*KSEL)             // 131072
#define OFF_IMP    (OFF_PROBS + NTOK*E_)     // 2228224
#define OFF_LOAD   (OFF_IMP + E_)            // 2228288

// workspace offsets (bytes)
#define WS_W32    0                          // 1024*64*4 = 256 KB ([d][e], refine)
#define WS_BSWH   262144                     // 128 KB bf16 hi, MFMA-frag order
#define WS_BSWL   393216                     // 128 KB bf16 lo
#define WS_LB64   524288                     // 4*64*8 = 2 KB  (zeroed w/ CNT)
#define WS_CNT    526336                     // 4
#define WS_LIST   526400                     // REFINE_CAP*4 = 32 KB

#define REFINE_CAP 8192
#define REFINE_EPS 3e-4f

typedef __attribute__((ext_vector_type(8))) short short8;
typedef __attribute__((ext_vector_type(4))) float f32x4;

// ---------------------------------------------------------------------------
// K_prep: UNCHANGED from R1 (isolate k_main attribution this round).
// 512 blocks, block bid owns 4 d's, full C in fp64, even/odd-c split chains.
// d<1024: wcomb32[d][e] + bf16 hi/lo split -> bsw slabs (MFMA-frag order)
// d>=1024: partial lbias[b][e] contributions via fp64 atomics (pre-reduced).
// ---------------------------------------------------------------------------
__global__ __launch_bounds__(256) void k_prep(const float* __restrict__ Wg,
                                              const float* __restrict__ Wc,
                                              const float* __restrict__ cond,
                                              float* __restrict__ wcomb32,
                                              short* __restrict__ bswH,
                                              short* __restrict__ bswL,
                                              double* __restrict__ lbias64,
                                              float* __restrict__ out) {
    __shared__ float wg_s[64 * 64];   // [c][e]  (transposed at stage)
    __shared__ float wc_s[64 * 4];    // [c][d_local]
    __shared__ double red[256];

    const int tid = threadIdx.x;
    const int e   = tid & 63;
    const int dg  = tid >> 6;                  // 0..3
    const int d0  = blockIdx.x * 4;

    if (blockIdx.x == 0 && tid < 2 * E_) out[OFF_IMP + tid] = 0.f;

    double ae = 0.0, ao = 0.0;                 // even / odd c chains

    for (int c0 = 0; c0 < C_; c0 += 64) {
        __syncthreads();
        // stage Wg chunk transposed: wg_s[c][e]
#pragma unroll
        for (int k = 0; k < 4; ++k) {
            int li = tid + k * 256;
            int r = li >> 4, c4 = (li & 15) * 4;
            float4 v = *(const float4*)&Wg[(size_t)r * 1024 + c0 + c4];
            wg_s[(c4 + 0) * 64 + r] = v.x;
            wg_s[(c4 + 1) * 64 + r] = v.y;
            wg_s[(c4 + 2) * 64 + r] = v.z;
            wg_s[(c4 + 3) * 64 + r] = v.w;
        }
        // stage Wc column slab: wc_s[c][dl], 256 floats (tid<128, float2 each)
        if (tid < 128) {
            int cc = tid >> 1, dd0 = (tid & 1) * 2;
            *(float2*)&wc_s[cc * 4 + dd0] =
                *(const float2*)&Wc[(size_t)(c0 + cc) * 2048 + d0 + dd0];
        }
        __syncthreads();
#pragma unroll 8
        for (int c = 0; c < 64; c += 2) {
            ae += (double)wg_s[(c + 0) * 64 + e] * (double)wc_s[(c + 0) * 4 + dg];
            ao += (double)wg_s[(c + 1) * 64 + e] * (double)wc_s[(c + 1) * 4 + dg];
        }
    }
    const double acc = ae + ao;

    if (d0 < 1024) {
        const int d = d0 + dg;
        const int et = e >> 4, nn = e & 15;
        float f = (float)acc;
        wcomb32[d * 64 + e] = f;
        unsigned u = __float_as_uint(f);
        short hi = (short)(u >> 16);
        float r = f - __uint_as_float(u & 0xFFFF0000u);
        short lo = (short)(__float_as_uint(r) >> 16);
        int kchunk = d >> 5, qsel = (d >> 3) & 3, j = d & 7;
        int idx = ((kchunk * 4 + et) * 64 + qsel * 16 + nn) * 8 + j;
        bswH[idx] = hi;
        bswL[idx] = lo;
    } else {
        const int da = d0 - 1024 + dg;
#pragma unroll
        for (int b = 0; b < 4; ++b) {
            double pb = (double)cond[b * 1024 + da] * acc;
            __syncthreads();
            red[tid] = pb;
            __syncthreads();
            if (tid < 64) {
                double s = red[tid] + red[tid + 64] + red[tid + 128] + red[tid + 192];
#if __has_builtin(__builtin_amdgcn_global_atomic_fadd_f64)
                unsafeAtomicAdd(&lbias64[b * 64 + tid], s);
#else
                atomicAdd(&lbias64[b * 64 + tid], s);
#endif
            }
        }
    }
}

// ---------------------------------------------------------------------------
// split 8 consecutive fp32 into bf16 hi + lo
// ---------------------------------------------------------------------------
__device__ __forceinline__ void split8(const float* xv, short8& h, short8& l) {
#pragma unroll
    for (int j = 0; j < 8; ++j) {
        unsigned u = __float_as_uint(xv[j]);
        h[j] = (short)(u >> 16);
        float r = xv[j] - __uint_as_float(u & 0xFFFF0000u);
        l[j] = (short)(__float_as_uint(r) >> 16);
    }
}

// ---------------------------------------------------------------------------
// K_main v3: logits = x @ Wcomb + lbias[b], bf16-split MFMA.
// 1024 blocks x 256 thr (4 blocks/CU, 16 waves/CU).
// BARRIER-FREE K-loop: each wave global-loads its OWN A fragments directly
// (8 contiguous floats per lane per kc; per-wave per-kc footprint = 16 rows
// x 128 B contiguous — L1/L2-served, x stays LLC-resident). No LDS staging,
// no ds_write, no __syncthreads until the epilogue -> 16 waves/CU free-run
// and cross-hide latency instead of locksteping at per-tile barriers.
// B-fragments for a whole tile (16 x short8 = 64 VGPR) are loaded in ONE
// batched burst before the MFMA phase -> ~1 L2 latency per tile instead of
// ~8 serialized ones (R1's VGPR=60 showed the compiler never prefetched).
// Wave (th,eh): 16 tokens x 32 experts, full K, 2 accumulators.
// A/B frag: [m|n=lane&15][k=(lane>>4)*8+j]; C/D: col=lane&15, row=(lane>>4)*4+r.
// ---------------------------------------------------------------------------
#define MT    32
#define ROWP  65          // epilogue logits row stride

__global__ __launch_bounds__(256, 4) void k_main(const float* __restrict__ x,
                                                 const short* __restrict__ bswH,
                                                 const short* __restrict__ bswL,
                                                 const double* __restrict__ lbias64,
                                                 float* __restrict__ out,
                                                 unsigned int* __restrict__ ref_cnt,
                                                 int* __restrict__ ref_list) {
    __shared__ float ls[MT * ROWP];   // 8.3 KB logits tile (epilogue only)
    __shared__ float invs[MT];
    __shared__ unsigned int cnts[E_];

    const int tid    = threadIdx.x;
    const int wid    = tid >> 6;
    const int lane   = tid & 63;
    const int nn     = lane & 15;
    const int qsel   = lane >> 4;
    const int th     = wid & 1;               // token half (0..1)
    const int eh     = wid >> 1;              // expert half (0..1)
    const int et0    = eh * 2;
    const int token0 = blockIdx.x * MT;
    const int b      = token0 >> 13;          // /8192

    if (tid < E_) cnts[tid] = 0;

    f32x4 acc[2];
#pragma unroll
    for (int ei = 0; ei < 2; ++ei) acc[ei] = (f32x4){0.f, 0.f, 0.f, 0.f};

    // this lane's A row slice base: row = token0 + th*16 + nn, col = qsel*8
    const float* arow = &x[(size_t)(token0 + th * 16 + nn) * 1024 + qsel * 8];
    const short* bh0  = bswH + (size_t)et0 * 512 + lane * 8;
    const short* bl0  = bswL + (size_t)et0 * 512 + lane * 8;

    for (int t = 0; t < 8; ++t) {     // K-tiles of 128, no barriers
        const int k0 = t * 128;
        // ---- batched B burst: all 16 fragments of this tile ----
        short8 Bh[4][2], Bl[4][2];
#pragma unroll
        for (int kc = 0; kc < 4; ++kc) {
            const size_t soff = (size_t)((t * 4 + kc) * 4) * 512;
#pragma unroll
            for (int ei = 0; ei < 2; ++ei) {
                Bh[kc][ei] = *(const short8*)(bh0 + soff + (size_t)ei * 512);
                Bl[kc][ei] = *(const short8*)(bl0 + soff + (size_t)ei * 512);
            }
        }
        // ---- compute: A direct from global (L1/L2), split, MFMA ----
#pragma unroll
        for (int kc = 0; kc < 4; ++kc) {
            float xv[8];
            *(f32x4*)&xv[0] = *(const f32x4*)(arow + k0 + kc * 32);
            *(f32x4*)&xv[4] = *(const f32x4*)(arow + k0 + kc * 32 + 4);
            short8 ah, al;
            split8(xv, ah, al);
#pragma unroll
            for (int ei = 0; ei < 2; ++ei) {
                acc[ei] = __builtin_amdgcn_mfma_f32_16x16x32_bf16(ah, Bh[kc][ei], acc[ei], 0, 0, 0);
                acc[ei] = __builtin_amdgcn_mfma_f32_16x16x32_bf16(ah, Bl[kc][ei], acc[ei], 0, 0, 0);
                acc[ei] = __builtin_amdgcn_mfma_f32_16x16x32_bf16(al, Bh[kc][ei], acc[ei], 0, 0, 0);
            }
        }
    }

    // ---- epilogue: logits into ls[tok][e] (stride ROWP) ----
    const int q4 = qsel * 4;
#pragma unroll
    for (int ei = 0; ei < 2; ++ei) {
        const int et = et0 + ei;
        float lb = (float)lbias64[b * 64 + et * 16 + nn];
#pragma unroll
        for (int r = 0; r < 4; ++r) {
            int tok = th * 16 + q4 + r;
            ls[tok * ROWP + et * 16 + nn] = acc[ei][r] + lb;
        }
    }
    __syncthreads();

    if (tid < MT) {
        const int tk = tid;
        const int base = tk * ROWP;
        float v1 = -1e30f, v2 = -1e30f, v3 = -1e30f;
        int i1 = 0, i2 = 0;
        for (int e = 0; e < E_; ++e) {
            float l = ls[base + e];
            if (l > v1)      { v3 = v2; v2 = v1; i2 = i1; v1 = l; i1 = e; }
            else if (l > v2) { v3 = v2; v2 = l; i2 = e; }
            else if (l > v3) { v3 = l; }
        }
        float sum = 0.f;
        for (int e = 0; e < E_; ++e) {
            float ex = __expf(ls[base + e] - v1);
            ls[base + e] = ex;
            sum += ex;
        }
        invs[tk] = 1.0f / sum;

        const int gt = token0 + tk;
        float s1 = 1.0f / (1.0f + __expf(v2 - v1));   // softmax over top-2
        *(float2*)&out[OFF_IDX + (size_t)gt * 2]    = make_float2((float)i1, (float)i2);
        *(float2*)&out[OFF_SCORES + (size_t)gt * 2] = make_float2(s1, 1.0f - s1);
        atomicAdd(&cnts[i1], 1u);
        atomicAdd(&cnts[i2], 1u);

        float g12 = v1 - v2, g23 = v2 - v3;
        float g = g12 < g23 ? g12 : g23;
        if (g < REFINE_EPS) {
            unsigned int pos = atomicAdd(ref_cnt, 1u);
            if (pos < REFINE_CAP) ref_list[pos] = gt;
        }
    }
    __syncthreads();

    // probs: 2048 floats = 512 float4, coalesced (2 per thread)
    float* probs = out + OFF_PROBS + (size_t)token0 * E_;
#pragma unroll
    for (int k = 0; k < 2; ++k) {
        int li4 = tid + k * 256;
        int tok = li4 >> 4;
        int c4 = (li4 & 15) << 2;
        float inv = invs[tok];
        int o = tok * ROWP + c4;
        *(float4*)&probs[(size_t)li4 * 4] =
            make_float4(ls[o] * inv, ls[o + 1] * inv,
                        ls[o + 2] * inv, ls[o + 3] * inv);
    }

    // importance + load: one atomic each per e per block
    if (tid < E_) {
        const int e = tid;
        float s = 0.f;
        for (int tt = 0; tt < MT; ++tt) s += ls[tt * ROWP + e] * invs[tt];
        atomicAdd(&out[OFF_IMP + e],  s * (1.0f / (float)NTOK));
        atomicAdd(&out[OFF_LOAD + e], (float)cnts[e] * (1.0f / (float)(NTOK * KSEL)));
    }
}

// ---------------------------------------------------------------------------
// K_ref: UNCHANGED. fp64 re-evaluation of ambiguous tokens, one wave/token.
// ---------------------------------------------------------------------------
__global__ __launch_bounds__(256) void k_refine(const float* __restrict__ x,
                                                const float* __restrict__ wcomb32,
                                                const double* __restrict__ lbias64,
                                                const unsigned int* __restrict__ ref_cnt,
                                                const int* __restrict__ ref_list,
                                                float* __restrict__ out) {
    int wave = (int)((blockIdx.x * blockDim.x + threadIdx.x) >> 6);
    int lane = threadIdx.x & 63;
    unsigned int n = *ref_cnt;
    if (n > REFINE_CAP) n = REFINE_CAP;
    const int nwaves = (int)((gridDim.x * blockDim.x) >> 6);

    for (unsigned int wi = wave; wi < n; wi += nwaves) {
        const int gt = ref_list[wi];
        const int b = gt / T_;
        const float* xrow = x + (size_t)gt * C_;
        double a0 = 0.0, a1 = 0.0, a2 = 0.0, a3 = 0.0;
        for (int d = 0; d < C_; d += 4) {
            a0 += (double)xrow[d + 0] * (double)wcomb32[(d + 0) * 64 + lane];
            a1 += (double)xrow[d + 1] * (double)wcomb32[(d + 1) * 64 + lane];
            a2 += (double)xrow[d + 2] * (double)wcomb32[(d + 2) * 64 + lane];
            a3 += (double)xrow[d + 3] * (double)wcomb32[(d + 3) * 64 + lane];
        }
        double acc = ((a0 + a1) + (a2 + a3)) + lbias64[b * 64 + lane];

        double v = acc; int id = lane;
        for (int off = 32; off > 0; off >>= 1) {
            double ov = __shfl_xor(v, off, 64);
            int oid   = __shfl_xor(id, off, 64);
            if (ov > v || (ov == v && oid < id)) { v = ov; id = oid; }
        }
        double v1 = v; int i1 = id;
        v = (lane == i1) ? -1e300 : acc; id = lane;
        for (int off = 32; off > 0; off >>= 1) {
            double ov = __shfl_xor(v, off, 64);
            int oid   = __shfl_xor(id, off, 64);
            if (ov > v || (ov == v && oid < id)) { v = ov; id = oid; }
        }
        double v2 = v; int i2 = id;

        if (lane == 0) {
            float s1 = (float)(1.0 / (1.0 + exp(v2 - v1)));
            *(float2*)&out[OFF_IDX + (size_t)gt * 2]    = make_float2((float)i1, (float)i2);
            *(float2*)&out[OFF_SCORES + (size_t)gt * 2] = make_float2(s1, 1.0f - s1);
        }
    }
}

// ---------------------------------------------------------------------------
extern "C" void kernel_launch(void* const* d_in, const int* in_sizes, int n_in,
                              void* d_out, int out_size, void* d_ws, size_t ws_size,
                              hipStream_t stream) {
    const float* x    = (const float*)d_in[0];   // (4,8192,1024)
    const float* cond = (const float*)d_in[1];   // (4,1024)
    const float* Wg   = (const float*)d_in[2];   // (64,1024)
    const float* Wc   = (const float*)d_in[3];   // (1024,2048)
    float* out = (float*)d_out;
    char*  ws  = (char*)d_ws;

    float*  wcomb32 = (float*)(ws + WS_W32);
    short*  bswH    = (short*)(ws + WS_BSWH);
    short*  bswL    = (short*)(ws + WS_BSWL);
    double* lbias64 = (double*)(ws + WS_LB64);
    unsigned int* ref_cnt = (unsigned int*)(ws + WS_CNT);
    int*    ref_list = (int*)(ws + WS_LIST);

    // zero lbias64 (2 KB) + ref_cnt (adjacent) in one memset
    hipMemsetAsync(ws + WS_LB64, 0, (WS_CNT - WS_LB64) + 64, stream);

    k_prep<<<512, 256, 0, stream>>>(Wg, Wc, cond, wcomb32, bswH, bswL, lbias64, out);
    k_main<<<NTOK / MT, 256, 0, stream>>>(x, bswH, bswL, lbias64, out, ref_cnt, ref_list);
    k_refine<<<256, 256, 0, stream>>>(x, wcomb32, lbias64, ref_cnt, ref_list, out);
}

// Round 3
// 345.599 us; speedup vs baseline: 1.0366x; 1.0366x over previous
//
#include <hip/hip_runtime.h>
#include <math.h>

#define B_    4
#define T_    8192
#define C_    1024
#define E_    64
#define NTOK  (B_*T_)          // 32768
#define KSEL  2

// d_out offsets (in floats): idx, scores, probs, importance, load
#define OFF_IDX    0
#define OFF_SCORES (NTOK*KSEL)               // 65536
#define OFF_PROBS  (2*NTOK*KSEL)             // 131072
#define OFF_IMP    (OFF_PROBS + NTOK*E_)     // 2228224
#define OFF_LOAD   (OFF_IMP + E_)            // 2228288

// workspace offsets (bytes)
#define WS_W32    0                          // 1024*64*4 = 256 KB ([d][e], refine)
#define WS_BSWH   262144                     // 128 KB bf16 hi, MFMA-frag order
#define WS_BSWL   393216                     // 128 KB bf16 lo
#define WS_LB64   524288                     // 4*64*8 = 2 KB  (zeroed w/ CNT)
#define WS_CNT    526336                     // 4
#define WS_LIST   526400                     // REFINE_CAP*4 = 32 KB

#define REFINE_CAP 8192
#define REFINE_EPS 3e-4f

typedef __attribute__((ext_vector_type(8))) short short8;
typedef __attribute__((ext_vector_type(4))) float f32x4;

// raw workgroup barrier (no vmcnt/lgkm drain), fenced against compiler motion
#define BAR() do { asm volatile("" ::: "memory"); \
                   __builtin_amdgcn_s_barrier();  \
                   asm volatile("" ::: "memory"); } while (0)

// ---------------------------------------------------------------------------
// K_prep: UNCHANGED (isolate k_main attribution).
// 512 blocks, block bid owns 4 d's, full C in fp64, even/odd-c split chains.
// ---------------------------------------------------------------------------
__global__ __launch_bounds__(256) void k_prep(const float* __restrict__ Wg,
                                              const float* __restrict__ Wc,
                                              const float* __restrict__ cond,
                                              float* __restrict__ wcomb32,
                                              short* __restrict__ bswH,
                                              short* __restrict__ bswL,
                                              double* __restrict__ lbias64,
                                              float* __restrict__ out) {
    __shared__ float wg_s[64 * 64];   // [c][e]  (transposed at stage)
    __shared__ float wc_s[64 * 4];    // [c][d_local]
    __shared__ double red[256];

    const int tid = threadIdx.x;
    const int e   = tid & 63;
    const int dg  = tid >> 6;                  // 0..3
    const int d0  = blockIdx.x * 4;

    if (blockIdx.x == 0 && tid < 2 * E_) out[OFF_IMP + tid] = 0.f;

    double ae = 0.0, ao = 0.0;                 // even / odd c chains

    for (int c0 = 0; c0 < C_; c0 += 64) {
        __syncthreads();
#pragma unroll
        for (int k = 0; k < 4; ++k) {
            int li = tid + k * 256;
            int r = li >> 4, c4 = (li & 15) * 4;
            float4 v = *(const float4*)&Wg[(size_t)r * 1024 + c0 + c4];
            wg_s[(c4 + 0) * 64 + r] = v.x;
            wg_s[(c4 + 1) * 64 + r] = v.y;
            wg_s[(c4 + 2) * 64 + r] = v.z;
            wg_s[(c4 + 3) * 64 + r] = v.w;
        }
        if (tid < 128) {
            int cc = tid >> 1, dd0 = (tid & 1) * 2;
            *(float2*)&wc_s[cc * 4 + dd0] =
                *(const float2*)&Wc[(size_t)(c0 + cc) * 2048 + d0 + dd0];
        }
        __syncthreads();
#pragma unroll 8
        for (int c = 0; c < 64; c += 2) {
            ae += (double)wg_s[(c + 0) * 64 + e] * (double)wc_s[(c + 0) * 4 + dg];
            ao += (double)wg_s[(c + 1) * 64 + e] * (double)wc_s[(c + 1) * 4 + dg];
        }
    }
    const double acc = ae + ao;

    if (d0 < 1024) {
        const int d = d0 + dg;
        const int et = e >> 4, nn = e & 15;
        float f = (float)acc;
        wcomb32[d * 64 + e] = f;
        unsigned u = __float_as_uint(f);
        short hi = (short)(u >> 16);
        float r = f - __uint_as_float(u & 0xFFFF0000u);
        short lo = (short)(__float_as_uint(r) >> 16);
        int kchunk = d >> 5, qsel = (d >> 3) & 3, j = d & 7;
        int idx = ((kchunk * 4 + et) * 64 + qsel * 16 + nn) * 8 + j;
        bswH[idx] = hi;
        bswL[idx] = lo;
    } else {
        const int da = d0 - 1024 + dg;
#pragma unroll
        for (int b = 0; b < 4; ++b) {
            double pb = (double)cond[b * 1024 + da] * acc;
            __syncthreads();
            red[tid] = pb;
            __syncthreads();
            if (tid < 64) {
                double s = red[tid] + red[tid + 64] + red[tid + 128] + red[tid + 192];
#if __has_builtin(__builtin_amdgcn_global_atomic_fadd_f64)
                unsafeAtomicAdd(&lbias64[b * 64 + tid], s);
#else
                atomicAdd(&lbias64[b * 64 + tid], s);
#endif
            }
        }
    }
}

// ---------------------------------------------------------------------------
// split 8 consecutive fp32 into bf16 hi + lo
// ---------------------------------------------------------------------------
__device__ __forceinline__ void split8(const float* xv, short8& h, short8& l) {
#pragma unroll
    for (int j = 0; j < 8; ++j) {
        unsigned u = __float_as_uint(xv[j]);
        h[j] = (short)(u >> 16);
        float r = xv[j] - __uint_as_float(u & 0xFFFF0000u);
        l[j] = (short)(__float_as_uint(r) >> 16);
    }
}

// ---------------------------------------------------------------------------
// K_main v4: async-DMA staged, XOR-swizzled, double-buffered.
// 1024 blocks x 256 thr (4 blocks/CU). Tile = 32 rows x 128 floats (16 KB),
// staged via global_load_lds width=16 (4 per wave per tile) — the DMA has no
// dest VGPR, so the compiler CANNOT sink it onto the dependence chain (the
// failure mode of R1/R2). Tile t+1 is issued before computing tile t;
// explicit s_waitcnt vmcnt(4) + raw s_barrier (no __syncthreads drain).
//
// LDS layout: linear rows of 512 B (required by global_load_lds), with a
// 16B-granule XOR swizzle  f_phys = f ^ (row&7)  applied on BOTH sides:
// writer pre-swizzles the per-lane GLOBAL source address (LDS dest stays
// linear: base + lane*16), reader applies the same XOR on its ds_read addr.
// Bank check: lane's first b128 starts at bank 4*((2*qsel)^(nn&7)) — all 8
// start positions hit -> uniform 8 accesses/bank = optimal for a 1KB move.
//
// Wave (th,eh): 16 tokens x 32 experts, full K, 2 accumulators.
// A/B frag: [m|n=lane&15][k=(lane>>4)*8+j]; C/D: col=lane&15, row=(lane>>4)*4+r.
// ---------------------------------------------------------------------------
#define MT    32
#define ROWP  65          // epilogue logits row stride (aliases buf0)

__device__ __forceinline__ void stage_tile(const float* __restrict__ x,
                                           float* xs, int token0, int t,
                                           int buf, int wid, int lane) {
#pragma unroll
    for (int p = 0; p < 4; ++p) {
        const int sbase = p * 256 + wid * 64;      // wave-uniform 16B-slot base
        const int s  = sbase + lane;
        const int r  = s >> 5;                     // row 0..31
        const int f  = (s & 31) ^ (r & 7);         // logical 16B granule
        const float* g = &x[(size_t)(token0 + r) * 1024 + t * 128 + f * 4];
        float* l = xs + buf * 4096 + sbase * 4;    // linear dest; HW adds lane*16B
        __builtin_amdgcn_global_load_lds(
            (const __attribute__((address_space(1))) unsigned int*)g,
            (__attribute__((address_space(3))) unsigned int*)l, 16, 0, 0);
    }
}

__global__ __launch_bounds__(256, 4) void k_main(const float* __restrict__ x,
                                                 const short* __restrict__ bswH,
                                                 const short* __restrict__ bswL,
                                                 const double* __restrict__ lbias64,
                                                 float* __restrict__ out,
                                                 unsigned int* __restrict__ ref_cnt,
                                                 int* __restrict__ ref_list) {
    __shared__ __align__(16) float xs[2 * 4096];  // 32 KB: 2 tile buffers; buf0 reused as logits
    __shared__ float invs[MT];
    __shared__ unsigned int cnts[E_];

    const int tid    = threadIdx.x;
    const int wid    = tid >> 6;
    const int lane   = tid & 63;
    const int nn     = lane & 15;
    const int qsel   = lane >> 4;
    const int th     = wid & 1;               // token half (0..1)
    const int eh     = wid >> 1;              // expert half (0..1)
    const int et0    = eh * 2;
    const int token0 = blockIdx.x * MT;
    const int b      = token0 >> 13;          // /8192

    if (tid < E_) cnts[tid] = 0;

    f32x4 acc[2];
#pragma unroll
    for (int ei = 0; ei < 2; ++ei) acc[ei] = (f32x4){0.f, 0.f, 0.f, 0.f};

    const short* bh0 = bswH + (size_t)et0 * 512 + lane * 8;
    const short* bl0 = bswL + (size_t)et0 * 512 + lane * 8;

    const int rr = th * 16 + nn;              // this lane's A row in the tile
    const int rx = rr & 7;                    // its XOR key

    // ---- prologue: stage tile 0 ----
    stage_tile(x, xs, token0, 0, 0, wid, lane);

    for (int t = 0; t < 8; ++t) {             // K-tiles of 128
        const int cur = t & 1;
        if (t < 7) stage_tile(x, xs, token0, t + 1, cur ^ 1, wid, lane);
        // own tile-t DMA done when <=4 outstanding (the 4 newest are t+1's)
        if (t < 7) asm volatile("s_waitcnt vmcnt(4)" ::: "memory");
        else       asm volatile("s_waitcnt vmcnt(0)" ::: "memory");
        BAR();                                 // all waves' tile-t loads landed

        const float* abase = xs + cur * 4096 + rr * 128;
#pragma unroll
        for (int kc = 0; kc < 4; ++kc) {
            const int f0 = kc * 8 + qsel * 2;  // logical 16B granule of 8-float slice
            float xv[8];
            *(f32x4*)&xv[0] = *(const f32x4*)(abase + (((f0    ) ^ rx) << 2));
            *(f32x4*)&xv[4] = *(const f32x4*)(abase + (((f0 + 1) ^ rx) << 2));
            short8 ah, al;
            split8(xv, ah, al);
            const size_t soff = (size_t)((t * 4 + kc) * 4) * 512;
#pragma unroll
            for (int ei = 0; ei < 2; ++ei) {
                short8 b_h = *(const short8*)(bh0 + soff + (size_t)ei * 512);
                short8 b_l = *(const short8*)(bl0 + soff + (size_t)ei * 512);
                acc[ei] = __builtin_amdgcn_mfma_f32_16x16x32_bf16(ah, b_h, acc[ei], 0, 0, 0);
                acc[ei] = __builtin_amdgcn_mfma_f32_16x16x32_bf16(ah, b_l, acc[ei], 0, 0, 0);
                acc[ei] = __builtin_amdgcn_mfma_f32_16x16x32_bf16(al, b_h, acc[ei], 0, 0, 0);
            }
        }
        BAR();                                 // all waves done reading buf[cur]
    }

    // ---- epilogue: logits into xs[tok][e] (stride ROWP, aliases buf0) ----
    const int q4 = qsel * 4;
#pragma unroll
    for (int ei = 0; ei < 2; ++ei) {
        const int et = et0 + ei;
        float lb = (float)lbias64[b * 64 + et * 16 + nn];
#pragma unroll
        for (int r = 0; r < 4; ++r) {
            int tok = th * 16 + q4 + r;
            xs[tok * ROWP + et * 16 + nn] = acc[ei][r] + lb;
        }
    }
    __syncthreads();

    if (tid < MT) {
        const int tk = tid;
        const int base = tk * ROWP;
        float v1 = -1e30f, v2 = -1e30f, v3 = -1e30f;
        int i1 = 0, i2 = 0;
        for (int e = 0; e < E_; ++e) {
            float l = xs[base + e];
            if (l > v1)      { v3 = v2; v2 = v1; i2 = i1; v1 = l; i1 = e; }
            else if (l > v2) { v3 = v2; v2 = l; i2 = e; }
            else if (l > v3) { v3 = l; }
        }
        float sum = 0.f;
        for (int e = 0; e < E_; ++e) {
            float ex = __expf(xs[base + e] - v1);
            xs[base + e] = ex;
            sum += ex;
        }
        invs[tk] = 1.0f / sum;

        const int gt = token0 + tk;
        float s1 = 1.0f / (1.0f + __expf(v2 - v1));   // softmax over top-2
        *(float2*)&out[OFF_IDX + (size_t)gt * 2]    = make_float2((float)i1, (float)i2);
        *(float2*)&out[OFF_SCORES + (size_t)gt * 2] = make_float2(s1, 1.0f - s1);
        atomicAdd(&cnts[i1], 1u);
        atomicAdd(&cnts[i2], 1u);

        float g12 = v1 - v2, g23 = v2 - v3;
        float g = g12 < g23 ? g12 : g23;
        if (g < REFINE_EPS) {
            unsigned int pos = atomicAdd(ref_cnt, 1u);
            if (pos < REFINE_CAP) ref_list[pos] = gt;
        }
    }
    __syncthreads();

    // probs: 2048 floats = 512 float4, coalesced (2 per thread)
    float* probs = out + OFF_PROBS + (size_t)token0 * E_;
#pragma unroll
    for (int k = 0; k < 2; ++k) {
        int li4 = tid + k * 256;
        int tok = li4 >> 4;
        int c4 = (li4 & 15) << 2;
        float inv = invs[tok];
        int o = tok * ROWP + c4;
        *(float4*)&probs[(size_t)li4 * 4] =
            make_float4(xs[o] * inv, xs[o + 1] * inv,
                        xs[o + 2] * inv, xs[o + 3] * inv);
    }

    // importance + load: one atomic each per e per block
    if (tid < E_) {
        const int e = tid;
        float s = 0.f;
        for (int tt = 0; tt < MT; ++tt) s += xs[tt * ROWP + e] * invs[tt];
        atomicAdd(&out[OFF_IMP + e],  s * (1.0f / (float)NTOK));
        atomicAdd(&out[OFF_LOAD + e], (float)cnts[e] * (1.0f / (float)(NTOK * KSEL)));
    }
}

// ---------------------------------------------------------------------------
// K_ref: UNCHANGED. fp64 re-evaluation of ambiguous tokens, one wave/token.
// ---------------------------------------------------------------------------
__global__ __launch_bounds__(256) void k_refine(const float* __restrict__ x,
                                                const float* __restrict__ wcomb32,
                                                const double* __restrict__ lbias64,
                                                const unsigned int* __restrict__ ref_cnt,
                                                const int* __restrict__ ref_list,
                                                float* __restrict__ out) {
    int wave = (int)((blockIdx.x * blockDim.x + threadIdx.x) >> 6);
    int lane = threadIdx.x & 63;
    unsigned int n = *ref_cnt;
    if (n > REFINE_CAP) n = REFINE_CAP;
    const int nwaves = (int)((gridDim.x * blockDim.x) >> 6);

    for (unsigned int wi = wave; wi < n; wi += nwaves) {
        const int gt = ref_list[wi];
        const int b = gt / T_;
        const float* xrow = x + (size_t)gt * C_;
        double a0 = 0.0, a1 = 0.0, a2 = 0.0, a3 = 0.0;
        for (int d = 0; d < C_; d += 4) {
            a0 += (double)xrow[d + 0] * (double)wcomb32[(d + 0) * 64 + lane];
            a1 += (double)xrow[d + 1] * (double)wcomb32[(d + 1) * 64 + lane];
            a2 += (double)xrow[d + 2] * (double)wcomb32[(d + 2) * 64 + lane];
            a3 += (double)xrow[d + 3] * (double)wcomb32[(d + 3) * 64 + lane];
        }
        double acc = ((a0 + a1) + (a2 + a3)) + lbias64[b * 64 + lane];

        double v = acc; int id = lane;
        for (int off = 32; off > 0; off >>= 1) {
            double ov = __shfl_xor(v, off, 64);
            int oid   = __shfl_xor(id, off, 64);
            if (ov > v || (ov == v && oid < id)) { v = ov; id = oid; }
        }
        double v1 = v; int i1 = id;
        v = (lane == i1) ? -1e300 : acc; id = lane;
        for (int off = 32; off > 0; off >>= 1) {
            double ov = __shfl_xor(v, off, 64);
            int oid   = __shfl_xor(id, off, 64);
            if (ov > v || (ov == v && oid < id)) { v = ov; id = oid; }
        }
        double v2 = v; int i2 = id;

        if (lane == 0) {
            float s1 = (float)(1.0 / (1.0 + exp(v2 - v1)));
            *(float2*)&out[OFF_IDX + (size_t)gt * 2]    = make_float2((float)i1, (float)i2);
            *(float2*)&out[OFF_SCORES + (size_t)gt * 2] = make_float2(s1, 1.0f - s1);
        }
    }
}

// ---------------------------------------------------------------------------
extern "C" void kernel_launch(void* const* d_in, const int* in_sizes, int n_in,
                              void* d_out, int out_size, void* d_ws, size_t ws_size,
                              hipStream_t stream) {
    const float* x    = (const float*)d_in[0];   // (4,8192,1024)
    const float* cond = (const float*)d_in[1];   // (4,1024)
    const float* Wg   = (const float*)d_in[2];   // (64,1024)
    const float* Wc   = (const float*)d_in[3];   // (1024,2048)
    float* out = (float*)d_out;
    char*  ws  = (char*)d_ws;

    float*  wcomb32 = (float*)(ws + WS_W32);
    short*  bswH    = (short*)(ws + WS_BSWH);
    short*  bswL    = (short*)(ws + WS_BSWL);
    double* lbias64 = (double*)(ws + WS_LB64);
    unsigned int* ref_cnt = (unsigned int*)(ws + WS_CNT);
    int*    ref_list = (int*)(ws + WS_LIST);

    // zero lbias64 (2 KB) + ref_cnt (adjacent) in one memset
    hipMemsetAsync(ws + WS_LB64, 0, (WS_CNT - WS_LB64) + 64, stream);

    k_prep<<<512, 256, 0, stream>>>(Wg, Wc, cond, wcomb32, bswH, bswL, lbias64, out);
    k_main<<<NTOK / MT, 256, 0, stream>>>(x, bswH, bswL, lbias64, out, ref_cnt, ref_list);
    k_refine<<<256, 256, 0, stream>>>(x, wcomb32, lbias64, ref_cnt, ref_list, out);
}

// Round 4
// 324.152 us; speedup vs baseline: 1.1052x; 1.0662x over previous
//
#include <hip/hip_runtime.h>
#include <math.h>

#define B_    4
#define T_    8192
#define C_    1024
#define E_    64
#define NTOK  (B_*T_)          // 32768
#define KSEL  2

// d_out offsets (in floats): idx, scores, probs, importance, load
#define OFF_IDX    0
#define OFF_SCORES (NTOK*KSEL)               // 65536
#define OFF_PROBS  (2*NTOK*KSEL)             // 131072
#define OFF_IMP    (OFF_PROBS + NTOK*E_)     // 2228224
#define OFF_LOAD   (OFF_IMP + E_)            // 2228288

// workspace offsets (bytes)
#define WS_W32    0                          // 1024*64*4 = 256 KB ([d][e], refine)
#define WS_BSWH   262144                     // 128 KB bf16 hi, MFMA-frag order
#define WS_BSWL   393216                     // 128 KB bf16 lo
#define WS_LB64   524288                     // 4*64*8 = 2 KB  (zeroed w/ CNT)
#define WS_CNT    526336                     // 4
#define WS_LIST   526400                     // REFINE_CAP*4 = 32 KB

#define REFINE_CAP 8192
#define REFINE_EPS 3e-4f

typedef __attribute__((ext_vector_type(8))) short short8;
typedef __attribute__((ext_vector_type(4))) float f32x4;

// raw workgroup barrier (no vmcnt/lgkm drain), fenced against compiler motion
#define BAR() do { asm volatile("" ::: "memory"); \
                   __builtin_amdgcn_s_barrier();  \
                   asm volatile("" ::: "memory"); } while (0)

// binding global load: compiler CANNOT sink/elide these (R2 failure mode)
#define GL0(dst, p)    asm volatile("global_load_dwordx4 %0, %1, off" \
                                    : "=v"(dst) : "v"(p) : "memory")
#define GL1K(dst, p)   asm volatile("global_load_dwordx4 %0, %1, off offset:1024" \
                                    : "=v"(dst) : "v"(p) : "memory")

// ---------------------------------------------------------------------------
// K_prep: UNCHANGED (isolate k_main attribution).
// 512 blocks, block bid owns 4 d's, full C in fp64, even/odd-c split chains.
// ---------------------------------------------------------------------------
__global__ __launch_bounds__(256) void k_prep(const float* __restrict__ Wg,
                                              const float* __restrict__ Wc,
                                              const float* __restrict__ cond,
                                              float* __restrict__ wcomb32,
                                              short* __restrict__ bswH,
                                              short* __restrict__ bswL,
                                              double* __restrict__ lbias64,
                                              float* __restrict__ out) {
    __shared__ float wg_s[64 * 64];   // [c][e]  (transposed at stage)
    __shared__ float wc_s[64 * 4];    // [c][d_local]
    __shared__ double red[256];

    const int tid = threadIdx.x;
    const int e   = tid & 63;
    const int dg  = tid >> 6;                  // 0..3
    const int d0  = blockIdx.x * 4;

    if (blockIdx.x == 0 && tid < 2 * E_) out[OFF_IMP + tid] = 0.f;

    double ae = 0.0, ao = 0.0;                 // even / odd c chains

    for (int c0 = 0; c0 < C_; c0 += 64) {
        __syncthreads();
#pragma unroll
        for (int k = 0; k < 4; ++k) {
            int li = tid + k * 256;
            int r = li >> 4, c4 = (li & 15) * 4;
            float4 v = *(const float4*)&Wg[(size_t)r * 1024 + c0 + c4];
            wg_s[(c4 + 0) * 64 + r] = v.x;
            wg_s[(c4 + 1) * 64 + r] = v.y;
            wg_s[(c4 + 2) * 64 + r] = v.z;
            wg_s[(c4 + 3) * 64 + r] = v.w;
        }
        if (tid < 128) {
            int cc = tid >> 1, dd0 = (tid & 1) * 2;
            *(float2*)&wc_s[cc * 4 + dd0] =
                *(const float2*)&Wc[(size_t)(c0 + cc) * 2048 + d0 + dd0];
        }
        __syncthreads();
#pragma unroll 8
        for (int c = 0; c < 64; c += 2) {
            ae += (double)wg_s[(c + 0) * 64 + e] * (double)wc_s[(c + 0) * 4 + dg];
            ao += (double)wg_s[(c + 1) * 64 + e] * (double)wc_s[(c + 1) * 4 + dg];
        }
    }
    const double acc = ae + ao;

    if (d0 < 1024) {
        const int d = d0 + dg;
        const int et = e >> 4, nn = e & 15;
        float f = (float)acc;
        wcomb32[d * 64 + e] = f;
        unsigned u = __float_as_uint(f);
        short hi = (short)(u >> 16);
        float r = f - __uint_as_float(u & 0xFFFF0000u);
        short lo = (short)(__float_as_uint(r) >> 16);
        int kchunk = d >> 5, qsel = (d >> 3) & 3, j = d & 7;
        int idx = ((kchunk * 4 + et) * 64 + qsel * 16 + nn) * 8 + j;
        bswH[idx] = hi;
        bswL[idx] = lo;
    } else {
        const int da = d0 - 1024 + dg;
#pragma unroll
        for (int b = 0; b < 4; ++b) {
            double pb = (double)cond[b * 1024 + da] * acc;
            __syncthreads();
            red[tid] = pb;
            __syncthreads();
            if (tid < 64) {
                double s = red[tid] + red[tid + 64] + red[tid + 128] + red[tid + 192];
#if __has_builtin(__builtin_amdgcn_global_atomic_fadd_f64)
                unsafeAtomicAdd(&lbias64[b * 64 + tid], s);
#else
                atomicAdd(&lbias64[b * 64 + tid], s);
#endif
            }
        }
    }
}

// ---------------------------------------------------------------------------
// split 8 consecutive fp32 into bf16 hi + lo
// ---------------------------------------------------------------------------
__device__ __forceinline__ void split8(const float* xv, short8& h, short8& l) {
#pragma unroll
    for (int j = 0; j < 8; ++j) {
        unsigned u = __float_as_uint(xv[j]);
        h[j] = (short)(u >> 16);
        float r = xv[j] - __uint_as_float(u & 0xFFFF0000u);
        l[j] = (short)(__float_as_uint(r) >> 16);
    }
}

// ---------------------------------------------------------------------------
// K_main v5: v4's DMA-staged, swizzled A path + BINDING asm B-batch.
// 1024 blocks x 256 thr (4 blocks/CU). Per K-tile:
//   1. 16 x asm-volatile global_load_dwordx4  -> B regs for tile t  (un-sinkable)
//   2. stage_tile(t+1): 4 x global_load_lds DMA (no dest VGPR, un-sinkable)
//   3. s_waitcnt vmcnt(4): B(t) + stage(t) landed; stage(t+1) still in flight
//      + sched_barrier(0) (rule #18: stop MFMA hoisting above the waitcnt)
//   4. raw s_barrier; compute t entirely from registers + LDS (zero waits)
// -> 1 exposed L2 latency per tile instead of ~8 serialized ones (the 7k-cyc/
//    tile wall measured in R3; VGPR=52 proved the compiler chained the loads).
// LDS: linear 512B rows (DMA requirement) + 16B-granule XOR swizzle
// f_phys = f ^ (row&7), pre-swizzled GLOBAL source + swizzled ds_read addr
// (both-sides involution, rule #21) — harness-verified in R3.
// Wave (th,eh): 16 tokens x 32 experts, full K, 2 accumulators.
// A/B frag: [m|n=lane&15][k=(lane>>4)*8+j]; C/D: col=lane&15, row=(lane>>4)*4+r.
// ---------------------------------------------------------------------------
#define MT    32
#define ROWP  65          // epilogue logits row stride (aliases buf0)

__device__ __forceinline__ void stage_tile(const float* __restrict__ x,
                                           float* xs, int token0, int t,
                                           int buf, int wid, int lane) {
#pragma unroll
    for (int p = 0; p < 4; ++p) {
        const int sbase = p * 256 + wid * 64;      // wave-uniform 16B-slot base
        const int s  = sbase + lane;
        const int r  = s >> 5;                     // row 0..31
        const int f  = (s & 31) ^ (r & 7);         // logical 16B granule
        const float* g = &x[(size_t)(token0 + r) * 1024 + t * 128 + f * 4];
        float* l = xs + buf * 4096 + sbase * 4;    // linear dest; HW adds lane*16B
        __builtin_amdgcn_global_load_lds(
            (const __attribute__((address_space(1))) unsigned int*)g,
            (__attribute__((address_space(3))) unsigned int*)l, 16, 0, 0);
    }
}

__global__ __launch_bounds__(256, 4) void k_main(const float* __restrict__ x,
                                                 const short* __restrict__ bswH,
                                                 const short* __restrict__ bswL,
                                                 const double* __restrict__ lbias64,
                                                 float* __restrict__ out,
                                                 unsigned int* __restrict__ ref_cnt,
                                                 int* __restrict__ ref_list) {
    __shared__ __align__(16) float xs[2 * 4096];  // 32 KB: 2 tile buffers; buf0 reused as logits
    __shared__ float invs[MT];
    __shared__ unsigned int cnts[E_];

    const int tid    = threadIdx.x;
    const int wid    = tid >> 6;
    const int lane   = tid & 63;
    const int nn     = lane & 15;
    const int qsel   = lane >> 4;
    const int th     = wid & 1;               // token half (0..1)
    const int eh     = wid >> 1;              // expert half (0..1)
    const int et0    = eh * 2;
    const int token0 = blockIdx.x * MT;
    const int b      = token0 >> 13;          // /8192

    if (tid < E_) cnts[tid] = 0;

    f32x4 acc[2];
#pragma unroll
    for (int ei = 0; ei < 2; ++ei) acc[ei] = (f32x4){0.f, 0.f, 0.f, 0.f};

    // byte base of this lane's B fragments: bsw + (et0*512 + lane*8) shorts
    const char* bh0 = (const char*)(bswH + (size_t)et0 * 512 + lane * 8);
    const char* bl0 = (const char*)(bswL + (size_t)et0 * 512 + lane * 8);

    const int rr = th * 16 + nn;              // this lane's A row in the tile
    const int rx = rr & 7;                    // its XOR key

    // ---- prologue: stage tile 0 ----
    stage_tile(x, xs, token0, 0, 0, wid, lane);

    for (int t = 0; t < 8; ++t) {             // K-tiles of 128
        const int cur = t & 1;

        // ---- 1. binding B-batch for tile t (16 loads, in-flight together) ----
        short8 Bh[4][2], Bl[4][2];
        {
            const char* bhT = bh0 + (size_t)t * 16384;   // (t*4+kc)*4096 + ei*1024
            const char* blT = bl0 + (size_t)t * 16384;
#pragma unroll
            for (int kc = 0; kc < 4; ++kc) {
                const char* ph = bhT + kc * 4096;
                const char* pl = blT + kc * 4096;
                GL0 (Bh[kc][0], ph);
                GL1K(Bh[kc][1], ph);
                GL0 (Bl[kc][0], pl);
                GL1K(Bl[kc][1], pl);
            }
        }
        // ---- 2. issue next A-tile DMA (flies across compute of t) ----
        if (t < 7) stage_tile(x, xs, token0, t + 1, cur ^ 1, wid, lane);
        // ---- 3. wait: B(t) + stage(t) done; stage(t+1) (4 newest) in flight ----
        if (t < 7) asm volatile("s_waitcnt vmcnt(4)" ::: "memory");
        else       asm volatile("s_waitcnt vmcnt(0)" ::: "memory");
        __builtin_amdgcn_sched_barrier(0);    // rule #18: nothing crosses the wait
        BAR();                                 // all waves' tile-t A landed

        // ---- 4. compute: zero memory waits inside ----
        const float* abase = xs + cur * 4096 + rr * 128;
#pragma unroll
        for (int kc = 0; kc < 4; ++kc) {
            const int f0 = kc * 8 + qsel * 2;  // logical 16B granule of 8-float slice
            float xv[8];
            *(f32x4*)&xv[0] = *(const f32x4*)(abase + (((f0    ) ^ rx) << 2));
            *(f32x4*)&xv[4] = *(const f32x4*)(abase + (((f0 + 1) ^ rx) << 2));
            short8 ah, al;
            split8(xv, ah, al);
#pragma unroll
            for (int ei = 0; ei < 2; ++ei) {
                acc[ei] = __builtin_amdgcn_mfma_f32_16x16x32_bf16(ah, Bh[kc][ei], acc[ei], 0, 0, 0);
                acc[ei] = __builtin_amdgcn_mfma_f32_16x16x32_bf16(ah, Bl[kc][ei], acc[ei], 0, 0, 0);
                acc[ei] = __builtin_amdgcn_mfma_f32_16x16x32_bf16(al, Bh[kc][ei], acc[ei], 0, 0, 0);
            }
        }
        BAR();                                 // all waves done reading buf[cur]
    }

    // ---- epilogue: logits into xs[tok][e] (stride ROWP, aliases buf0) ----
    const int q4 = qsel * 4;
#pragma unroll
    for (int ei = 0; ei < 2; ++ei) {
        const int et = et0 + ei;
        float lb = (float)lbias64[b * 64 + et * 16 + nn];
#pragma unroll
        for (int r = 0; r < 4; ++r) {
            int tok = th * 16 + q4 + r;
            xs[tok * ROWP + et * 16 + nn] = acc[ei][r] + lb;
        }
    }
    __syncthreads();

    if (tid < MT) {
        const int tk = tid;
        const int base = tk * ROWP;
        float v1 = -1e30f, v2 = -1e30f, v3 = -1e30f;
        int i1 = 0, i2 = 0;
        for (int e = 0; e < E_; ++e) {
            float l = xs[base + e];
            if (l > v1)      { v3 = v2; v2 = v1; i2 = i1; v1 = l; i1 = e; }
            else if (l > v2) { v3 = v2; v2 = l; i2 = e; }
            else if (l > v3) { v3 = l; }
        }
        float sum = 0.f;
        for (int e = 0; e < E_; ++e) {
            float ex = __expf(xs[base + e] - v1);
            xs[base + e] = ex;
            sum += ex;
        }
        invs[tk] = 1.0f / sum;

        const int gt = token0 + tk;
        float s1 = 1.0f / (1.0f + __expf(v2 - v1));   // softmax over top-2
        *(float2*)&out[OFF_IDX + (size_t)gt * 2]    = make_float2((float)i1, (float)i2);
        *(float2*)&out[OFF_SCORES + (size_t)gt * 2] = make_float2(s1, 1.0f - s1);
        atomicAdd(&cnts[i1], 1u);
        atomicAdd(&cnts[i2], 1u);

        float g12 = v1 - v2, g23 = v2 - v3;
        float g = g12 < g23 ? g12 : g23;
        if (g < REFINE_EPS) {
            unsigned int pos = atomicAdd(ref_cnt, 1u);
            if (pos < REFINE_CAP) ref_list[pos] = gt;
        }
    }
    __syncthreads();

    // probs: 2048 floats = 512 float4, coalesced (2 per thread)
    float* probs = out + OFF_PROBS + (size_t)token0 * E_;
#pragma unroll
    for (int k = 0; k < 2; ++k) {
        int li4 = tid + k * 256;
        int tok = li4 >> 4;
        int c4 = (li4 & 15) << 2;
        float inv = invs[tok];
        int o = tok * ROWP + c4;
        *(float4*)&probs[(size_t)li4 * 4] =
            make_float4(xs[o] * inv, xs[o + 1] * inv,
                        xs[o + 2] * inv, xs[o + 3] * inv);
    }

    // importance + load: one atomic each per e per block
    if (tid < E_) {
        const int e = tid;
        float s = 0.f;
        for (int tt = 0; tt < MT; ++tt) s += xs[tt * ROWP + e] * invs[tt];
        atomicAdd(&out[OFF_IMP + e],  s * (1.0f / (float)NTOK));
        atomicAdd(&out[OFF_LOAD + e], (float)cnts[e] * (1.0f / (float)(NTOK * KSEL)));
    }
}

// ---------------------------------------------------------------------------
// K_ref: UNCHANGED. fp64 re-evaluation of ambiguous tokens, one wave/token.
// ---------------------------------------------------------------------------
__global__ __launch_bounds__(256) void k_refine(const float* __restrict__ x,
                                                const float* __restrict__ wcomb32,
                                                const double* __restrict__ lbias64,
                                                const unsigned int* __restrict__ ref_cnt,
                                                const int* __restrict__ ref_list,
                                                float* __restrict__ out) {
    int wave = (int)((blockIdx.x * blockDim.x + threadIdx.x) >> 6);
    int lane = threadIdx.x & 63;
    unsigned int n = *ref_cnt;
    if (n > REFINE_CAP) n = REFINE_CAP;
    const int nwaves = (int)((gridDim.x * blockDim.x) >> 6);

    for (unsigned int wi = wave; wi < n; wi += nwaves) {
        const int gt = ref_list[wi];
        const int b = gt / T_;
        const float* xrow = x + (size_t)gt * C_;
        double a0 = 0.0, a1 = 0.0, a2 = 0.0, a3 = 0.0;
        for (int d = 0; d < C_; d += 4) {
            a0 += (double)xrow[d + 0] * (double)wcomb32[(d + 0) * 64 + lane];
            a1 += (double)xrow[d + 1] * (double)wcomb32[(d + 1) * 64 + lane];
            a2 += (double)xrow[d + 2] * (double)wcomb32[(d + 2) * 64 + lane];
            a3 += (double)xrow[d + 3] * (double)wcomb32[(d + 3) * 64 + lane];
        }
        double acc = ((a0 + a1) + (a2 + a3)) + lbias64[b * 64 + lane];

        double v = acc; int id = lane;
        for (int off = 32; off > 0; off >>= 1) {
            double ov = __shfl_xor(v, off, 64);
            int oid   = __shfl_xor(id, off, 64);
            if (ov > v || (ov == v && oid < id)) { v = ov; id = oid; }
        }
        double v1 = v; int i1 = id;
        v = (lane == i1) ? -1e300 : acc; id = lane;
        for (int off = 32; off > 0; off >>= 1) {
            double ov = __shfl_xor(v, off, 64);
            int oid   = __shfl_xor(id, off, 64);
            if (ov > v || (ov == v && oid < id)) { v = ov; id = oid; }
        }
        double v2 = v; int i2 = id;

        if (lane == 0) {
            float s1 = (float)(1.0 / (1.0 + exp(v2 - v1)));
            *(float2*)&out[OFF_IDX + (size_t)gt * 2]    = make_float2((float)i1, (float)i2);
            *(float2*)&out[OFF_SCORES + (size_t)gt * 2] = make_float2(s1, 1.0f - s1);
        }
    }
}

// ---------------------------------------------------------------------------
extern "C" void kernel_launch(void* const* d_in, const int* in_sizes, int n_in,
                              void* d_out, int out_size, void* d_ws, size_t ws_size,
                              hipStream_t stream) {
    const float* x    = (const float*)d_in[0];   // (4,8192,1024)
    const float* cond = (const float*)d_in[1];   // (4,1024)
    const float* Wg   = (const float*)d_in[2];   // (64,1024)
    const float* Wc   = (const float*)d_in[3];   // (1024,2048)
    float* out = (float*)d_out;
    char*  ws  = (char*)d_ws;

    float*  wcomb32 = (float*)(ws + WS_W32);
    short*  bswH    = (short*)(ws + WS_BSWH);
    short*  bswL    = (short*)(ws + WS_BSWL);
    double* lbias64 = (double*)(ws + WS_LB64);
    unsigned int* ref_cnt = (unsigned int*)(ws + WS_CNT);
    int*    ref_list = (int*)(ws + WS_LIST);

    // zero lbias64 (2 KB) + ref_cnt (adjacent) in one memset
    hipMemsetAsync(ws + WS_LB64, 0, (WS_CNT - WS_LB64) + 64, stream);

    k_prep<<<512, 256, 0, stream>>>(Wg, Wc, cond, wcomb32, bswH, bswL, lbias64, out);
    k_main<<<NTOK / MT, 256, 0, stream>>>(x, bswH, bswL, lbias64, out, ref_cnt, ref_list);
    k_refine<<<256, 256, 0, stream>>>(x, wcomb32, lbias64, ref_cnt, ref_list, out);
}

// Round 5
// 322.403 us; speedup vs baseline: 1.1112x; 1.0054x over previous
//
#include <hip/hip_runtime.h>
#include <math.h>

#define B_    4
#define T_    8192
#define C_    1024
#define E_    64
#define NTOK  (B_*T_)          // 32768
#define KSEL  2

// d_out offsets (in floats): idx, scores, probs, importance, load
#define OFF_IDX    0
#define OFF_SCORES (NTOK*KSEL)               // 65536
#define OFF_PROBS  (2*NTOK*KSEL)             // 131072
#define OFF_IMP    (OFF_PROBS + NTOK*E_)     // 2228224
#define OFF_LOAD   (OFF_IMP + E_)            // 2228288

// workspace offsets (bytes)
#define WS_W32    0                          // 1024*64*4 = 256 KB ([d][e], refine)
#define WS_BSWH   262144                     // 128 KB bf16 hi, MFMA-frag order
#define WS_BSWL   393216                     // 128 KB bf16 lo
#define WS_LB64   524288                     // 4*64*8 = 2 KB  (zeroed w/ CNT)
#define WS_CNT    526336                     // 4
#define WS_LIST   526400                     // REFINE_CAP*4 = 32 KB

#define REFINE_CAP 8192
#define REFINE_EPS 3e-4f

typedef __attribute__((ext_vector_type(8))) short short8;
typedef __attribute__((ext_vector_type(4))) float f32x4;

// raw workgroup barrier (no vmcnt/lgkm drain), fenced against compiler motion
#define BAR() do { asm volatile("" ::: "memory"); \
                   __builtin_amdgcn_s_barrier();  \
                   asm volatile("" ::: "memory"); } while (0)

// binding global load: compiler CANNOT sink/elide these (R2 failure mode)
#define GL0(dst, p)    asm volatile("global_load_dwordx4 %0, %1, off" \
                                    : "=v"(dst) : "v"(p) : "memory")
#define GL1K(dst, p)   asm volatile("global_load_dwordx4 %0, %1, off offset:1024" \
                                    : "=v"(dst) : "v"(p) : "memory")

// load one half-tile of B fragments (kc = kcbase, kcbase+1; ei = 0,1; hi+lo)
// 8 binding loads, all in flight together.
#define LOAD_BHALF(Bh_, Bl_, tt, kcbase) do {                                \
    const char* ph_ = bh0 + (size_t)(tt) * 16384 + (kcbase) * 4096;          \
    const char* pl_ = bl0 + (size_t)(tt) * 16384 + (kcbase) * 4096;          \
    GL0 (Bh_[0][0], ph_);        GL1K(Bh_[0][1], ph_);                       \
    GL0 (Bl_[0][0], pl_);        GL1K(Bl_[0][1], pl_);                       \
    GL0 (Bh_[1][0], ph_ + 4096); GL1K(Bh_[1][1], ph_ + 4096);                \
    GL0 (Bl_[1][0], pl_ + 4096); GL1K(Bl_[1][1], pl_ + 4096);                \
} while (0)

// ---------------------------------------------------------------------------
// K_prep: UNCHANGED (isolation: any total delta attributes to k_main).
// ---------------------------------------------------------------------------
__global__ __launch_bounds__(256) void k_prep(const float* __restrict__ Wg,
                                              const float* __restrict__ Wc,
                                              const float* __restrict__ cond,
                                              float* __restrict__ wcomb32,
                                              short* __restrict__ bswH,
                                              short* __restrict__ bswL,
                                              double* __restrict__ lbias64,
                                              float* __restrict__ out) {
    __shared__ float wg_s[64 * 64];   // [c][e]  (transposed at stage)
    __shared__ float wc_s[64 * 4];    // [c][d_local]
    __shared__ double red[256];

    const int tid = threadIdx.x;
    const int e   = tid & 63;
    const int dg  = tid >> 6;                  // 0..3
    const int d0  = blockIdx.x * 4;

    if (blockIdx.x == 0 && tid < 2 * E_) out[OFF_IMP + tid] = 0.f;

    double ae = 0.0, ao = 0.0;                 // even / odd c chains

    for (int c0 = 0; c0 < C_; c0 += 64) {
        __syncthreads();
#pragma unroll
        for (int k = 0; k < 4; ++k) {
            int li = tid + k * 256;
            int r = li >> 4, c4 = (li & 15) * 4;
            float4 v = *(const float4*)&Wg[(size_t)r * 1024 + c0 + c4];
            wg_s[(c4 + 0) * 64 + r] = v.x;
            wg_s[(c4 + 1) * 64 + r] = v.y;
            wg_s[(c4 + 2) * 64 + r] = v.z;
            wg_s[(c4 + 3) * 64 + r] = v.w;
        }
        if (tid < 128) {
            int cc = tid >> 1, dd0 = (tid & 1) * 2;
            *(float2*)&wc_s[cc * 4 + dd0] =
                *(const float2*)&Wc[(size_t)(c0 + cc) * 2048 + d0 + dd0];
        }
        __syncthreads();
#pragma unroll 8
        for (int c = 0; c < 64; c += 2) {
            ae += (double)wg_s[(c + 0) * 64 + e] * (double)wc_s[(c + 0) * 4 + dg];
            ao += (double)wg_s[(c + 1) * 64 + e] * (double)wc_s[(c + 1) * 4 + dg];
        }
    }
    const double acc = ae + ao;

    if (d0 < 1024) {
        const int d = d0 + dg;
        const int et = e >> 4, nn = e & 15;
        float f = (float)acc;
        wcomb32[d * 64 + e] = f;
        unsigned u = __float_as_uint(f);
        short hi = (short)(u >> 16);
        float r = f - __uint_as_float(u & 0xFFFF0000u);
        short lo = (short)(__float_as_uint(r) >> 16);
        int kchunk = d >> 5, qsel = (d >> 3) & 3, j = d & 7;
        int idx = ((kchunk * 4 + et) * 64 + qsel * 16 + nn) * 8 + j;
        bswH[idx] = hi;
        bswL[idx] = lo;
    } else {
        const int da = d0 - 1024 + dg;
#pragma unroll
        for (int b = 0; b < 4; ++b) {
            double pb = (double)cond[b * 1024 + da] * acc;
            __syncthreads();
            red[tid] = pb;
            __syncthreads();
            if (tid < 64) {
                double s = red[tid] + red[tid + 64] + red[tid + 128] + red[tid + 192];
#if __has_builtin(__builtin_amdgcn_global_atomic_fadd_f64)
                unsafeAtomicAdd(&lbias64[b * 64 + tid], s);
#else
                atomicAdd(&lbias64[b * 64 + tid], s);
#endif
            }
        }
    }
}

// ---------------------------------------------------------------------------
// split 8 consecutive fp32 into bf16 hi + lo
// ---------------------------------------------------------------------------
__device__ __forceinline__ void split8(const float* xv, short8& h, short8& l) {
#pragma unroll
    for (int j = 0; j < 8; ++j) {
        unsigned u = __float_as_uint(xv[j]);
        h[j] = (short)(u >> 16);
        float r = xv[j] - __uint_as_float(u & 0xFFFF0000u);
        l[j] = (short)(__float_as_uint(r) >> 16);
    }
}

// ---------------------------------------------------------------------------
// K_main v6: v5 + half-tile B software pipeline with counted vmcnt (T4).
// v5 exposed one full L2 latency per tile (B issued ~80 cyc before its
// vmcnt). Now every wait targets loads issued >=1 compute-phase earlier:
//   per tile t: issue B2nd(t); issue DMA(t+1); vmcnt(12) [waits B1st(t) +
//   stage(t), both issued one phase/tile ago; leaves B2nd(t)+stage(t+1) in
//   flight]; BAR; compute kc0,1; issue B1st(t+1); vmcnt(12) [waits B2nd(t),
//   issued one phase ago]; compute kc2,3; BAR.
// Steady-state memory waits ~0. t=7 drains with vmcnt(8)/vmcnt(0).
// __launch_bounds__(256,3): ~120-VGPR body must not spill (cap 128 at ,4
// was borderline); pipeline no longer needs 4-block cross-hiding.
// MFMA accumulation order identical to v5 -> bitwise-same results.
// A path (DMA + XOR swizzle) unchanged and harness-verified since R3.
// ---------------------------------------------------------------------------
#define MT    32
#define ROWP  65          // epilogue logits row stride (aliases buf0)

__device__ __forceinline__ void stage_tile(const float* __restrict__ x,
                                           float* xs, int token0, int t,
                                           int buf, int wid, int lane) {
#pragma unroll
    for (int p = 0; p < 4; ++p) {
        const int sbase = p * 256 + wid * 64;      // wave-uniform 16B-slot base
        const int s  = sbase + lane;
        const int r  = s >> 5;                     // row 0..31
        const int f  = (s & 31) ^ (r & 7);         // logical 16B granule
        const float* g = &x[(size_t)(token0 + r) * 1024 + t * 128 + f * 4];
        float* l = xs + buf * 4096 + sbase * 4;    // linear dest; HW adds lane*16B
        __builtin_amdgcn_global_load_lds(
            (const __attribute__((address_space(1))) unsigned int*)g,
            (__attribute__((address_space(3))) unsigned int*)l, 16, 0, 0);
    }
}

__device__ __forceinline__ void compute_half(const float* abase, int kc0,
                                             int qsel, int rx,
                                             short8 (&Bh_)[2][2], short8 (&Bl_)[2][2],
                                             f32x4 (&acc)[2]) {
#pragma unroll
    for (int k2 = 0; k2 < 2; ++k2) {
        const int f0 = (kc0 + k2) * 8 + qsel * 2;
        float xv[8];
        *(f32x4*)&xv[0] = *(const f32x4*)(abase + (((f0    ) ^ rx) << 2));
        *(f32x4*)&xv[4] = *(const f32x4*)(abase + (((f0 + 1) ^ rx) << 2));
        short8 ah, al;
        split8(xv, ah, al);
#pragma unroll
        for (int ei = 0; ei < 2; ++ei) {
            acc[ei] = __builtin_amdgcn_mfma_f32_16x16x32_bf16(ah, Bh_[k2][ei], acc[ei], 0, 0, 0);
            acc[ei] = __builtin_amdgcn_mfma_f32_16x16x32_bf16(ah, Bl_[k2][ei], acc[ei], 0, 0, 0);
            acc[ei] = __builtin_amdgcn_mfma_f32_16x16x32_bf16(al, Bh_[k2][ei], acc[ei], 0, 0, 0);
        }
    }
}

__global__ __launch_bounds__(256, 3) void k_main(const float* __restrict__ x,
                                                 const short* __restrict__ bswH,
                                                 const short* __restrict__ bswL,
                                                 const double* __restrict__ lbias64,
                                                 float* __restrict__ out,
                                                 unsigned int* __restrict__ ref_cnt,
                                                 int* __restrict__ ref_list) {
    __shared__ __align__(16) float xs[2 * 4096];  // 32 KB: 2 tile buffers; buf0 reused as logits
    __shared__ float invs[MT];
    __shared__ unsigned int cnts[E_];

    const int tid    = threadIdx.x;
    const int wid    = tid >> 6;
    const int lane   = tid & 63;
    const int nn     = lane & 15;
    const int qsel   = lane >> 4;
    const int th     = wid & 1;               // token half (0..1)
    const int eh     = wid >> 1;              // expert half (0..1)
    const int et0    = eh * 2;
    const int token0 = blockIdx.x * MT;
    const int b      = token0 >> 13;          // /8192

    if (tid < E_) cnts[tid] = 0;

    f32x4 acc[2];
#pragma unroll
    for (int ei = 0; ei < 2; ++ei) acc[ei] = (f32x4){0.f, 0.f, 0.f, 0.f};

    // byte base of this lane's B fragments: bsw + (et0*512 + lane*8) shorts
    const char* bh0 = (const char*)(bswH + (size_t)et0 * 512 + lane * 8);
    const char* bl0 = (const char*)(bswL + (size_t)et0 * 512 + lane * 8);

    const int rr = th * 16 + nn;              // this lane's A row in the tile
    const int rx = rr & 7;                    // its XOR key

    // B register double-buffer: half A = kc{0,1}, half B = kc{2,3}
    short8 BhA[2][2], BlA[2][2], BhB[2][2], BlB[2][2];

    // ---- prologue: stage tile 0 DMA, then first B half of tile 0 ----
    stage_tile(x, xs, token0, 0, 0, wid, lane);
    LOAD_BHALF(BhA, BlA, 0, 0);

    for (int t = 0; t < 8; ++t) {             // K-tiles of 128
        const int cur = t & 1;

        LOAD_BHALF(BhB, BlB, t, 2);                        // second half of t
        if (t < 7) stage_tile(x, xs, token0, t + 1, cur ^ 1, wid, lane);

        // wait: B1st(t) + stage(t) done; keep B2nd(t)[8] + stage(t+1)[4]
        if (t < 7) asm volatile("s_waitcnt vmcnt(12)" ::: "memory");
        else       asm volatile("s_waitcnt vmcnt(8)"  ::: "memory");
        __builtin_amdgcn_sched_barrier(0);    // rule #18: nothing crosses the wait
        BAR();                                 // all waves' tile-t A landed

        const float* abase = xs + cur * 4096 + rr * 128;
        compute_half(abase, 0, qsel, rx, BhA, BlA, acc);

        if (t < 7) LOAD_BHALF(BhA, BlA, t + 1, 0);         // first half of t+1

        // wait: B2nd(t) done; keep stage(t+1)[4] + B1st(t+1)[8]
        if (t < 7) asm volatile("s_waitcnt vmcnt(12)" ::: "memory");
        else       asm volatile("s_waitcnt vmcnt(0)"  ::: "memory");
        __builtin_amdgcn_sched_barrier(0);

        compute_half(abase, 2, qsel, rx, BhB, BlB, acc);

        BAR();                                 // all waves done reading buf[cur]
    }

    // ---- epilogue: logits into xs[tok][e] (stride ROWP, aliases buf0) ----
    const int q4 = qsel * 4;
#pragma unroll
    for (int ei = 0; ei < 2; ++ei) {
        const int et = et0 + ei;
        float lb = (float)lbias64[b * 64 + et * 16 + nn];
#pragma unroll
        for (int r = 0; r < 4; ++r) {
            int tok = th * 16 + q4 + r;
            xs[tok * ROWP + et * 16 + nn] = acc[ei][r] + lb;
        }
    }
    __syncthreads();

    if (tid < MT) {
        const int tk = tid;
        const int base = tk * ROWP;
        float v1 = -1e30f, v2 = -1e30f, v3 = -1e30f;
        int i1 = 0, i2 = 0;
        for (int e = 0; e < E_; ++e) {
            float l = xs[base + e];
            if (l > v1)      { v3 = v2; v2 = v1; i2 = i1; v1 = l; i1 = e; }
            else if (l > v2) { v3 = v2; v2 = l; i2 = e; }
            else if (l > v3) { v3 = l; }
        }
        float sum = 0.f;
        for (int e = 0; e < E_; ++e) {
            float ex = __expf(xs[base + e] - v1);
            xs[base + e] = ex;
            sum += ex;
        }
        invs[tk] = 1.0f / sum;

        const int gt = token0 + tk;
        float s1 = 1.0f / (1.0f + __expf(v2 - v1));   // softmax over top-2
        *(float2*)&out[OFF_IDX + (size_t)gt * 2]    = make_float2((float)i1, (float)i2);
        *(float2*)&out[OFF_SCORES + (size_t)gt * 2] = make_float2(s1, 1.0f - s1);
        atomicAdd(&cnts[i1], 1u);
        atomicAdd(&cnts[i2], 1u);

        float g12 = v1 - v2, g23 = v2 - v3;
        float g = g12 < g23 ? g12 : g23;
        if (g < REFINE_EPS) {
            unsigned int pos = atomicAdd(ref_cnt, 1u);
            if (pos < REFINE_CAP) ref_list[pos] = gt;
        }
    }
    __syncthreads();

    // probs: 2048 floats = 512 float4, coalesced (2 per thread)
    float* probs = out + OFF_PROBS + (size_t)token0 * E_;
#pragma unroll
    for (int k = 0; k < 2; ++k) {
        int li4 = tid + k * 256;
        int tok = li4 >> 4;
        int c4 = (li4 & 15) << 2;
        float inv = invs[tok];
        int o = tok * ROWP + c4;
        *(float4*)&probs[(size_t)li4 * 4] =
            make_float4(xs[o] * inv, xs[o + 1] * inv,
                        xs[o + 2] * inv, xs[o + 3] * inv);
    }

    // importance + load: one atomic each per e per block
    if (tid < E_) {
        const int e = tid;
        float s = 0.f;
        for (int tt = 0; tt < MT; ++tt) s += xs[tt * ROWP + e] * invs[tt];
        atomicAdd(&out[OFF_IMP + e],  s * (1.0f / (float)NTOK));
        atomicAdd(&out[OFF_LOAD + e], (float)cnts[e] * (1.0f / (float)(NTOK * KSEL)));
    }
}

// ---------------------------------------------------------------------------
// K_ref: UNCHANGED. fp64 re-evaluation of ambiguous tokens, one wave/token.
// ---------------------------------------------------------------------------
__global__ __launch_bounds__(256) void k_refine(const float* __restrict__ x,
                                                const float* __restrict__ wcomb32,
                                                const double* __restrict__ lbias64,
                                                const unsigned int* __restrict__ ref_cnt,
                                                const int* __restrict__ ref_list,
                                                float* __restrict__ out) {
    int wave = (int)((blockIdx.x * blockDim.x + threadIdx.x) >> 6);
    int lane = threadIdx.x & 63;
    unsigned int n = *ref_cnt;
    if (n > REFINE_CAP) n = REFINE_CAP;
    const int nwaves = (int)((gridDim.x * blockDim.x) >> 6);

    for (unsigned int wi = wave; wi < n; wi += nwaves) {
        const int gt = ref_list[wi];
        const int b = gt / T_;
        const float* xrow = x + (size_t)gt * C_;
        double a0 = 0.0, a1 = 0.0, a2 = 0.0, a3 = 0.0;
        for (int d = 0; d < C_; d += 4) {
            a0 += (double)xrow[d + 0] * (double)wcomb32[(d + 0) * 64 + lane];
            a1 += (double)xrow[d + 1] * (double)wcomb32[(d + 1) * 64 + lane];
            a2 += (double)xrow[d + 2] * (double)wcomb32[(d + 2) * 64 + lane];
            a3 += (double)xrow[d + 3] * (double)wcomb32[(d + 3) * 64 + lane];
        }
        double acc = ((a0 + a1) + (a2 + a3)) + lbias64[b * 64 + lane];

        double v = acc; int id = lane;
        for (int off = 32; off > 0; off >>= 1) {
            double ov = __shfl_xor(v, off, 64);
            int oid   = __shfl_xor(id, off, 64);
            if (ov > v || (ov == v && oid < id)) { v = ov; id = oid; }
        }
        double v1 = v; int i1 = id;
        v = (lane == i1) ? -1e300 : acc; id = lane;
        for (int off = 32; off > 0; off >>= 1) {
            double ov = __shfl_xor(v, off, 64);
            int oid   = __shfl_xor(id, off, 64);
            if (ov > v || (ov == v && oid < id)) { v = ov; id = oid; }
        }
        double v2 = v; int i2 = id;

        if (lane == 0) {
            float s1 = (float)(1.0 / (1.0 + exp(v2 - v1)));
            *(float2*)&out[OFF_IDX + (size_t)gt * 2]    = make_float2((float)i1, (float)i2);
            *(float2*)&out[OFF_SCORES + (size_t)gt * 2] = make_float2(s1, 1.0f - s1);
        }
    }
}

// ---------------------------------------------------------------------------
extern "C" void kernel_launch(void* const* d_in, const int* in_sizes, int n_in,
                              void* d_out, int out_size, void* d_ws, size_t ws_size,
                              hipStream_t stream) {
    const float* x    = (const float*)d_in[0];   // (4,8192,1024)
    const float* cond = (const float*)d_in[1];   // (4,1024)
    const float* Wg   = (const float*)d_in[2];   // (64,1024)
    const float* Wc   = (const float*)d_in[3];   // (1024,2048)
    float* out = (float*)d_out;
    char*  ws  = (char*)d_ws;

    float*  wcomb32 = (float*)(ws + WS_W32);
    short*  bswH    = (short*)(ws + WS_BSWH);
    short*  bswL    = (short*)(ws + WS_BSWL);
    double* lbias64 = (double*)(ws + WS_LB64);
    unsigned int* ref_cnt = (unsigned int*)(ws + WS_CNT);
    int*    ref_list = (int*)(ws + WS_LIST);

    // zero lbias64 (2 KB) + ref_cnt (adjacent) in one memset
    hipMemsetAsync(ws + WS_LB64, 0, (WS_CNT - WS_LB64) + 64, stream);

    k_prep<<<512, 256, 0, stream>>>(Wg, Wc, cond, wcomb32, bswH, bswL, lbias64, out);
    k_main<<<NTOK / MT, 256, 0, stream>>>(x, bswH, bswL, lbias64, out, ref_cnt, ref_list);
    k_refine<<<256, 256, 0, stream>>>(x, wcomb32, lbias64, ref_cnt, ref_list, out);
}